// Round 6
// baseline (146.116 us; speedup 1.0000x reference)
//
#include <hip/hip_runtime.h>
#include <math.h>

// TripleAttention: B=1, N=384, C=D=64, H=1.
// out[i,d] = num/den,
//   num[i,d] = sum_{j,k} R[i,j] P[i,k] Q[j,k] v1[j,d] v2[k,d]
//   den[i]   = sum_{j,k} R[i,j] P[i,k] Q[j,k]
// R=exp(AB), P=exp(CD), Q=exp(EF); reference's global-max shift cancels in the
// ratio. Main contraction: bf16 MFMA, hi/lo split (3 products) ~2^-16 accuracy.
// Round 6: MFMA dependency fix — B-frags cached in regs, then 3 passes of 15
// INDEPENDENT MFMAs (dep reuse distance 1 -> 15) to fill the matrix pipe.

#define NN 384

using short8 = __attribute__((ext_vector_type(8))) short;
using f32x4  = __attribute__((ext_vector_type(4))) float;
typedef unsigned short u16;
typedef unsigned int u32;

// ---------------- kernel 1: proj = x @ W^T  [384,512]; also v1t/v2t ----------------
__global__ void proj_kernel(const float* __restrict__ x, const float* __restrict__ W,
                            float* __restrict__ proj, float* __restrict__ v1t,
                            float* __restrict__ v2t) {
    int n = blockIdx.x;
    __shared__ float xs[64];
    if (threadIdx.x < 64) xs[threadIdx.x] = x[n * 64 + threadIdx.x];
    __syncthreads();
    const float4* xv4 = (const float4*)xs;
    for (int r = 0; r < 2; ++r) {
        int o = threadIdx.x + r * 256;
        const float4* w4 = (const float4*)(W + o * 64);
        float s = 0.f;
#pragma unroll
        for (int c = 0; c < 16; ++c) {
            float4 wv = w4[c];
            float4 xv = xv4[c];
            s += wv.x * xv.x + wv.y * xv.y + wv.z * xv.z + wv.w * xv.w;
        }
        proj[n * 512 + o] = s;
        if (o >= 448)      v2t[(o - 448) * NN + n] = s;   // v2^T [d][k]
        else if (o >= 384) v1t[(o - 384) * NN + n] = s;   // v1^T [d][j]
    }
}

// ---------------- kernel 2: scores + exp (+ bf16 split for Q) ----------------
__global__ void scores_exp_kernel(const float* __restrict__ proj,
                                  float* __restrict__ R, float* __restrict__ P,
                                  u16* __restrict__ Qhi, u16* __restrict__ Qlo) {
    int m = blockIdx.z;
    int bi = blockIdx.y, bj = blockIdx.x;
    int tid = threadIdx.x;
    int tx = tid % 16, ty = tid / 16;
    int aoff, boff;
    if (m == 0)      { aoff = 0;   boff = 64;  }
    else if (m == 1) { aoff = 128; boff = 192; }
    else             { aoff = 256; boff = 320; }

    __shared__ float As[32][65], Bs[32][65];
    for (int r = 0; r < 8; ++r) {
        int idx = tid + r * 256;
        int row = idx / 64, col = idx % 64;
        As[row][col] = proj[(bi * 32 + row) * 512 + aoff + col];
        Bs[row][col] = proj[(bj * 32 + row) * 512 + boff + col];
    }
    __syncthreads();

    float acc[2][2] = {{0.f, 0.f}, {0.f, 0.f}};
#pragma unroll 8
    for (int d = 0; d < 64; ++d) {
        float a0 = As[ty * 2][d], a1 = As[ty * 2 + 1][d];
        float b0 = Bs[tx * 2][d], b1 = Bs[tx * 2 + 1][d];
        acc[0][0] += a0 * b0; acc[0][1] += a0 * b1;
        acc[1][0] += a1 * b0; acc[1][1] += a1 * b1;
    }
#pragma unroll
    for (int a = 0; a < 2; ++a) {
        int row = bi * 32 + ty * 2 + a;
        int col = bj * 32 + tx * 2;
        float v0 = expf(acc[a][0] * 0.125f);
        float v1 = expf(acc[a][1] * 0.125f);
        if (m == 0) {
            R[row * NN + col] = v0; R[row * NN + col + 1] = v1;
        } else if (m == 1) {
            P[row * NN + col] = v0; P[row * NN + col + 1] = v1;
        } else {
            u32 b0 = __float_as_uint(v0), b1 = __float_as_uint(v1);
            u32 h0 = b0 & 0xFFFF0000u,   h1 = b1 & 0xFFFF0000u;
            float l0 = v0 - __uint_as_float(h0);
            float l1 = v1 - __uint_as_float(h1);
            ushort2 hw, lw;
            hw.x = (u16)(h0 >> 16); hw.y = (u16)(h1 >> 16);
            lw.x = (u16)(__float_as_uint(l0) >> 16);
            lw.y = (u16)(__float_as_uint(l1) >> 16);
            *(ushort2*)(Qhi + row * NN + col) = hw;
            *(ushort2*)(Qlo + row * NN + col) = lw;
        }
    }
}

#define MFMA(A, B, C) __builtin_amdgcn_mfma_f32_16x16x32_bf16(A, B, C, 0, 0, 0)

// ---------------- kernel 3: main MFMA contraction ----------------
// block = (i, jh): M=192 (j), N=80 (64 d + den col 64 + 15 zero), K=384.
// A (Q hi/lo) and v2t prefetched into ping/pong VGPRs 2-3 k-steps ahead.
// Inner step: 10 ds_read_b128 -> regs, then hh/hl/lh passes of 15 indep MFMAs.
__global__ __launch_bounds__(256, 3) void main_mfma(
    const u16* __restrict__ Qhi, const u16* __restrict__ Qlo,
    const float* __restrict__ R, const float* __restrict__ P,
    const float* __restrict__ v1t, const float* __restrict__ v2t,
    float* __restrict__ num0, float* __restrict__ num1,
    float* __restrict__ den0, float* __restrict__ den1) {
    int i  = blockIdx.x >> 1;
    int jh = blockIdx.x & 1;
    int tid = (int)threadIdx.x;
    int w = tid >> 6, l = tid & 63;
    int lr = l & 15, lc = l >> 4;
    int j0 = jh * 192 + w * 48;
    int kkq = (tid & 3) * 8;                 // BUILD k-offset within step
    int nB  = tid >> 2;                      // BUILD n-row (0..63)

    __shared__ float p_s[NN];
    __shared__ u16 Bh[2][80 * 40];
    __shared__ u16 Bl[2][80 * 40];
    __shared__ float sh[4][80];

    p_s[tid] = P[i * NN + tid];
    if (tid < 128) p_s[256 + tid] = P[i * NN + 256 + tid];
    // zero den-pad rows 65..79 of all 4 buffers once
    for (int z = tid; z < 1200; z += 256) {
        int m = z / 300, r = z % 300;
        u32* base = (u32*)((m & 1) ? Bl[m >> 1] : Bh[m >> 1]);
        base[1300 + r] = 0u;
    }

    const u16* qh_base = Qhi + (j0 + lr) * NN + lc * 8;
    const u16* ql_base = Qlo + (j0 + lr) * NN + lc * 8;
    const float* vt_base = v2t + nB * NN + kkq;

    f32x4 acc[3][5];
#pragma unroll
    for (int mf = 0; mf < 3; ++mf)
#pragma unroll
        for (int nf = 0; nf < 5; ++nf)
            acc[mf][nf] = (f32x4){0.f, 0.f, 0.f, 0.f};

    auto LOADA = [&](short8* H, short8* L, int t) {
#pragma unroll
        for (int mf = 0; mf < 3; ++mf) {
            H[mf] = *(const short8*)(qh_base + mf * 16 * NN + t * 32);
            L[mf] = *(const short8*)(ql_base + mf * 16 * NN + t * 32);
        }
    };
    auto LOADV = [&](float4& a, float4& b, int t) {
        a = *(const float4*)(vt_base + t * 32);
        b = *(const float4*)(vt_base + t * 32 + 4);
    };
    // BUILD from registers: VALU + ds_write only (p_s via LDS broadcast)
    auto BUILDW = [&](int buf, float4 va, float4 vb, int t) {
        int krel = t * 32;
        const float* pp = p_s + krel + kkq;
        float pr[8] = {va.x * pp[0], va.y * pp[1], va.z * pp[2], va.w * pp[3],
                       vb.x * pp[4], vb.y * pp[5], vb.z * pp[6], vb.w * pp[7]};
        u32* dh = (u32*)&Bh[buf][nB * 40 + kkq];
        u32* dl = (u32*)&Bl[buf][nB * 40 + kkq];
#pragma unroll
        for (int e = 0; e < 4; ++e) {
            float x0 = pr[2 * e], x1 = pr[2 * e + 1];
            u32 h0 = __float_as_uint(x0) & 0xFFFF0000u;
            u32 h1 = __float_as_uint(x1) & 0xFFFF0000u;
            float l0 = x0 - __uint_as_float(h0);
            float l1 = x1 - __uint_as_float(h1);
            dh[e] = (h0 >> 16) | h1;
            dl[e] = (__float_as_uint(l0) >> 16) |
                    (__float_as_uint(l1) & 0xFFFF0000u);
        }
        if (tid < 4) {       // den column 64: B = P
            const float* pq = p_s + krel + tid * 8;
            u32* eh = (u32*)&Bh[buf][64 * 40 + tid * 8];
            u32* el = (u32*)&Bl[buf][64 * 40 + tid * 8];
#pragma unroll
            for (int e = 0; e < 4; ++e) {
                float x0 = pq[2 * e], x1 = pq[2 * e + 1];
                u32 h0 = __float_as_uint(x0) & 0xFFFF0000u;
                u32 h1 = __float_as_uint(x1) & 0xFFFF0000u;
                float l0 = x0 - __uint_as_float(h0);
                float l1 = x1 - __uint_as_float(h1);
                eh[e] = (h0 >> 16) | h1;
                el[e] = (__float_as_uint(l0) >> 16) |
                        (__float_as_uint(l1) & 0xFFFF0000u);
            }
        }
    };
    // 10 LDS reads -> regs, then 3 passes of 15 independent MFMAs.
    // Per-accumulator order stays hh, hl, lh (bitwise-identical results).
    auto MFMASTEP = [&](int b, short8* aH, short8* aL) {
        short8 bh[5], bl[5];
#pragma unroll
        for (int nf = 0; nf < 5; ++nf) {
            bh[nf] = *(const short8*)&Bh[b][(nf * 16 + lr) * 40 + lc * 8];
            bl[nf] = *(const short8*)&Bl[b][(nf * 16 + lr) * 40 + lc * 8];
        }
#pragma unroll
        for (int nf = 0; nf < 5; ++nf)
#pragma unroll
            for (int mf = 0; mf < 3; ++mf)
                acc[mf][nf] = MFMA(aH[mf], bh[nf], acc[mf][nf]);
#pragma unroll
        for (int nf = 0; nf < 5; ++nf)
#pragma unroll
            for (int mf = 0; mf < 3; ++mf)
                acc[mf][nf] = MFMA(aH[mf], bl[nf], acc[mf][nf]);
#pragma unroll
        for (int nf = 0; nf < 5; ++nf)
#pragma unroll
            for (int mf = 0; mf < 3; ++mf)
                acc[mf][nf] = MFMA(aL[mf], bh[nf], acc[mf][nf]);
    };

    // ping/pong register stages: slot parity == step parity
    short8 aH0[3], aL0[3], aH1[3], aL1[3];
    float4 vA0, vB0, vA1, vB1;

    LOADA(aH0, aL0, 0); LOADA(aH1, aL1, 1);
    LOADV(vA0, vB0, 0); LOADV(vA1, vB1, 1);
    __syncthreads();                 // p_s + zero-pads visible
    BUILDW(0, vA0, vB0, 0);          // only stall-on-load BUILD (prologue)
    LOADV(vA0, vB0, 2);
    __syncthreads();                 // buf0 visible

#pragma unroll
    for (int tt = 0; tt < 6; ++tt) {
        int t0 = tt * 2, t1 = tt * 2 + 1;
        // even step t0: MFMA buf0/slot0; BUILD t0+1 -> buf1 from slot1
        BUILDW(1, vA1, vB1, t0 + 1);
        if (t0 + 3 <= 11) LOADV(vA1, vB1, t0 + 3);
        MFMASTEP(0, aH0, aL0);
        if (t0 + 2 <= 11) LOADA(aH0, aL0, t0 + 2);
        __syncthreads();
        // odd step t1: MFMA buf1/slot1; BUILD t1+1 -> buf0 from slot0
        if (t1 < 11) BUILDW(0, vA0, vB0, t1 + 1);
        if (t1 + 3 <= 11) LOADV(vA0, vB0, t1 + 3);
        MFMASTEP(1, aH1, aL1);
        if (t1 + 2 <= 11) LOADA(aH1, aL1, t1 + 2);
        __syncthreads();
    }

    // epilogue: s[n] = sum over this wave's 48 j of R*v1*T ; den via col 64.
    // acc[mf][nf] reg r <-> j = j0+mf*16+lc*4+r, col = nf*16+lr.
    float4 rj[3];
#pragma unroll
    for (int mf = 0; mf < 3; ++mf)
        rj[mf] = *(const float4*)(R + i * NN + j0 + mf * 16 + lc * 4);

#pragma unroll
    for (int nf = 0; nf < 5; ++nf) {
        float s = 0.f;
#pragma unroll
        for (int mf = 0; mf < 3; ++mf) {
            f32x4 a = acc[mf][nf];
            if (nf < 4) {
                const float* vp = v1t + (nf * 16 + lr) * NN + j0 + mf * 16 + lc * 4;
                float4 v1v = *(const float4*)vp;
                s += a[0] * rj[mf].x * v1v.x + a[1] * rj[mf].y * v1v.y
                   + a[2] * rj[mf].z * v1v.z + a[3] * rj[mf].w * v1v.w;
            } else {
                s += a[0] * rj[mf].x + a[1] * rj[mf].y
                   + a[2] * rj[mf].z + a[3] * rj[mf].w;
            }
        }
        s += __shfl_xor(s, 16, 64);
        s += __shfl_xor(s, 32, 64);
        if (l < 16) sh[w][nf * 16 + l] = s;
    }
    __syncthreads();
    if (tid < 80) {
        float v = sh[0][tid] + sh[1][tid] + sh[2][tid] + sh[3][tid];
        if (tid < 64) (jh ? num1 : num0)[i * 64 + tid] = v;
        else if (tid == 64) (jh ? den1 : den0)[i] = v;
    }
}

// ---------------- kernel 4: out = (num0+num1)/(den0+den1) ----------------
__global__ void finalize_kernel(const float* __restrict__ num0, const float* __restrict__ num1,
                                const float* __restrict__ den0, const float* __restrict__ den1,
                                float* __restrict__ out) {
    int idx = blockIdx.x * 256 + threadIdx.x;   // 24576
    int i = idx >> 6;
    out[idx] = (num0[idx] + num1[idx]) / (den0[i] + den1[i]);
}

extern "C" void kernel_launch(void* const* d_in, const int* in_sizes, int n_in,
                              void* d_out, int out_size, void* d_ws, size_t ws_size,
                              hipStream_t stream) {
    const float* x = (const float*)d_in[0];      // [1,384,64]
    const float* W = (const float*)d_in[1];      // [512,64]
    float* out = (float*)d_out;                  // [384,64]

    float* ws   = (float*)d_ws;
    float* R    = ws;                            // 147456
    float* P    = ws + 147456;                   // 147456
    float* v1t  = ws + 294912;                   // 24576  [64][384]
    float* v2t  = ws + 319488;                   // 24576  [64][384]
    u16*   Qhi  = (u16*)(ws + 344064);           // 147456 u16
    u16*   Qlo  = (u16*)(ws + 417792);           // 147456 u16
    float* proj = ws + 491520;                   // 196608
    // partials alias proj (proj dead after scores_exp)
    float* num0 = proj;                          // 24576
    float* num1 = proj + 24576;                  // 24576
    float* den0 = proj + 49152;                  // 384
    float* den1 = proj + 49536;                  // 384

    proj_kernel<<<NN, 256, 0, stream>>>(x, W, proj, v1t, v2t);
    scores_exp_kernel<<<dim3(12, 12, 3), 256, 0, stream>>>(proj, R, P, Qhi, Qlo);
    main_mfma<<<768, 256, 0, stream>>>(Qhi, Qlo, R, P, v1t, v2t,
                                       num0, num1, den0, den1);
    finalize_kernel<<<96, 256, 0, stream>>>(num0, num1, den0, den1, out);
}

// Round 7
// 110.252 us; speedup vs baseline: 1.3253x; 1.3253x over previous
//
#include <hip/hip_runtime.h>
#include <math.h>

// TripleAttention: B=1, N=384, C=D=64, H=1.
// out[i,d] = num/den,
//   num[i,d] = sum_{j,k} R[i,j] P[i,k] Q[j,k] v1[j,d] v2[k,d]
//   den[i]   = sum_{j,k} R[i,j] P[i,k] Q[j,k]
// R=exp(AB), P=exp(CD), Q=exp(EF); reference's global-max shift cancels in the
// ratio. Main contraction: bf16 MFMA, hi/lo split (3 products) ~2^-16 accuracy.
// Round 7: dep-distance-15 MFMA passes WITHOUT the round-6 spill — one 5-reg
// B-frag array, passes ordered hh / lh / (reload) / hl so only 20 extra VGPRs
// stay live (round 6's 40 spilled to scratch: WRITE_SIZE 116MB).

#define NN 384

using short8 = __attribute__((ext_vector_type(8))) short;
using f32x4  = __attribute__((ext_vector_type(4))) float;
typedef unsigned short u16;
typedef unsigned int u32;

// ---------------- kernel 1: proj = x @ W^T  [384,512]; also v1t/v2t ----------------
__global__ void proj_kernel(const float* __restrict__ x, const float* __restrict__ W,
                            float* __restrict__ proj, float* __restrict__ v1t,
                            float* __restrict__ v2t) {
    int n = blockIdx.x;
    __shared__ float xs[64];
    if (threadIdx.x < 64) xs[threadIdx.x] = x[n * 64 + threadIdx.x];
    __syncthreads();
    const float4* xv4 = (const float4*)xs;
    for (int r = 0; r < 2; ++r) {
        int o = threadIdx.x + r * 256;
        const float4* w4 = (const float4*)(W + o * 64);
        float s = 0.f;
#pragma unroll
        for (int c = 0; c < 16; ++c) {
            float4 wv = w4[c];
            float4 xv = xv4[c];
            s += wv.x * xv.x + wv.y * xv.y + wv.z * xv.z + wv.w * xv.w;
        }
        proj[n * 512 + o] = s;
        if (o >= 448)      v2t[(o - 448) * NN + n] = s;   // v2^T [d][k]
        else if (o >= 384) v1t[(o - 384) * NN + n] = s;   // v1^T [d][j]
    }
}

// ---------------- kernel 2: scores + exp (+ bf16 split for Q) ----------------
__global__ void scores_exp_kernel(const float* __restrict__ proj,
                                  float* __restrict__ R, float* __restrict__ P,
                                  u16* __restrict__ Qhi, u16* __restrict__ Qlo) {
    int m = blockIdx.z;
    int bi = blockIdx.y, bj = blockIdx.x;
    int tid = threadIdx.x;
    int tx = tid % 16, ty = tid / 16;
    int aoff, boff;
    if (m == 0)      { aoff = 0;   boff = 64;  }
    else if (m == 1) { aoff = 128; boff = 192; }
    else             { aoff = 256; boff = 320; }

    __shared__ float As[32][65], Bs[32][65];
    for (int r = 0; r < 8; ++r) {
        int idx = tid + r * 256;
        int row = idx / 64, col = idx % 64;
        As[row][col] = proj[(bi * 32 + row) * 512 + aoff + col];
        Bs[row][col] = proj[(bj * 32 + row) * 512 + boff + col];
    }
    __syncthreads();

    float acc[2][2] = {{0.f, 0.f}, {0.f, 0.f}};
#pragma unroll 8
    for (int d = 0; d < 64; ++d) {
        float a0 = As[ty * 2][d], a1 = As[ty * 2 + 1][d];
        float b0 = Bs[tx * 2][d], b1 = Bs[tx * 2 + 1][d];
        acc[0][0] += a0 * b0; acc[0][1] += a0 * b1;
        acc[1][0] += a1 * b0; acc[1][1] += a1 * b1;
    }
#pragma unroll
    for (int a = 0; a < 2; ++a) {
        int row = bi * 32 + ty * 2 + a;
        int col = bj * 32 + tx * 2;
        float v0 = expf(acc[a][0] * 0.125f);
        float v1 = expf(acc[a][1] * 0.125f);
        if (m == 0) {
            R[row * NN + col] = v0; R[row * NN + col + 1] = v1;
        } else if (m == 1) {
            P[row * NN + col] = v0; P[row * NN + col + 1] = v1;
        } else {
            u32 b0 = __float_as_uint(v0), b1 = __float_as_uint(v1);
            u32 h0 = b0 & 0xFFFF0000u,   h1 = b1 & 0xFFFF0000u;
            float l0 = v0 - __uint_as_float(h0);
            float l1 = v1 - __uint_as_float(h1);
            ushort2 hw, lw;
            hw.x = (u16)(h0 >> 16); hw.y = (u16)(h1 >> 16);
            lw.x = (u16)(__float_as_uint(l0) >> 16);
            lw.y = (u16)(__float_as_uint(l1) >> 16);
            *(ushort2*)(Qhi + row * NN + col) = hw;
            *(ushort2*)(Qlo + row * NN + col) = lw;
        }
    }
}

#define MFMA(A, B, C) __builtin_amdgcn_mfma_f32_16x16x32_bf16(A, B, C, 0, 0, 0)

// ---------------- kernel 3: main MFMA contraction ----------------
// block = (i, jh): M=192 (j), N=80 (64 d + den col 64 + 15 zero), K=384.
// A (Q hi/lo) and v2t prefetched into ping/pong VGPRs 2-3 k-steps ahead.
// Inner step: 5 ds_read_b128 (Bh) -> regs, 15 indep MFMAs (A-hi), 15 indep
// MFMAs (A-lo), reload regs from Bl, 15 indep MFMAs (A-hi).
__global__ __launch_bounds__(256, 3) void main_mfma(
    const u16* __restrict__ Qhi, const u16* __restrict__ Qlo,
    const float* __restrict__ R, const float* __restrict__ P,
    const float* __restrict__ v1t, const float* __restrict__ v2t,
    float* __restrict__ num0, float* __restrict__ num1,
    float* __restrict__ den0, float* __restrict__ den1) {
    int i  = blockIdx.x >> 1;
    int jh = blockIdx.x & 1;
    int tid = (int)threadIdx.x;
    int w = tid >> 6, l = tid & 63;
    int lr = l & 15, lc = l >> 4;
    int j0 = jh * 192 + w * 48;
    int kkq = (tid & 3) * 8;                 // BUILD k-offset within step
    int nB  = tid >> 2;                      // BUILD n-row (0..63)

    __shared__ float p_s[NN];
    __shared__ u16 Bh[2][80 * 40];
    __shared__ u16 Bl[2][80 * 40];
    __shared__ float sh[4][80];

    p_s[tid] = P[i * NN + tid];
    if (tid < 128) p_s[256 + tid] = P[i * NN + 256 + tid];
    // zero den-pad rows 65..79 of all 4 buffers once
    for (int z = tid; z < 1200; z += 256) {
        int m = z / 300, r = z % 300;
        u32* base = (u32*)((m & 1) ? Bl[m >> 1] : Bh[m >> 1]);
        base[1300 + r] = 0u;
    }

    const u16* qh_base = Qhi + (j0 + lr) * NN + lc * 8;
    const u16* ql_base = Qlo + (j0 + lr) * NN + lc * 8;
    const float* vt_base = v2t + nB * NN + kkq;

    f32x4 acc[3][5];
#pragma unroll
    for (int mf = 0; mf < 3; ++mf)
#pragma unroll
        for (int nf = 0; nf < 5; ++nf)
            acc[mf][nf] = (f32x4){0.f, 0.f, 0.f, 0.f};

    auto LOADA = [&](short8* H, short8* L, int t) {
#pragma unroll
        for (int mf = 0; mf < 3; ++mf) {
            H[mf] = *(const short8*)(qh_base + mf * 16 * NN + t * 32);
            L[mf] = *(const short8*)(ql_base + mf * 16 * NN + t * 32);
        }
    };
    auto LOADV = [&](float4& a, float4& b, int t) {
        a = *(const float4*)(vt_base + t * 32);
        b = *(const float4*)(vt_base + t * 32 + 4);
    };
    // BUILD from registers: VALU + ds_write only (p_s via LDS broadcast)
    auto BUILDW = [&](int buf, float4 va, float4 vb, int t) {
        int krel = t * 32;
        const float* pp = p_s + krel + kkq;
        float pr[8] = {va.x * pp[0], va.y * pp[1], va.z * pp[2], va.w * pp[3],
                       vb.x * pp[4], vb.y * pp[5], vb.z * pp[6], vb.w * pp[7]};
        u32* dh = (u32*)&Bh[buf][nB * 40 + kkq];
        u32* dl = (u32*)&Bl[buf][nB * 40 + kkq];
#pragma unroll
        for (int e = 0; e < 4; ++e) {
            float x0 = pr[2 * e], x1 = pr[2 * e + 1];
            u32 h0 = __float_as_uint(x0) & 0xFFFF0000u;
            u32 h1 = __float_as_uint(x1) & 0xFFFF0000u;
            float l0 = x0 - __uint_as_float(h0);
            float l1 = x1 - __uint_as_float(h1);
            dh[e] = (h0 >> 16) | h1;
            dl[e] = (__float_as_uint(l0) >> 16) |
                    (__float_as_uint(l1) & 0xFFFF0000u);
        }
        if (tid < 4) {       // den column 64: B = P
            const float* pq = p_s + krel + tid * 8;
            u32* eh = (u32*)&Bh[buf][64 * 40 + tid * 8];
            u32* el = (u32*)&Bl[buf][64 * 40 + tid * 8];
#pragma unroll
            for (int e = 0; e < 4; ++e) {
                float x0 = pq[2 * e], x1 = pq[2 * e + 1];
                u32 h0 = __float_as_uint(x0) & 0xFFFF0000u;
                u32 h1 = __float_as_uint(x1) & 0xFFFF0000u;
                float l0 = x0 - __uint_as_float(h0);
                float l1 = x1 - __uint_as_float(h1);
                eh[e] = (h0 >> 16) | h1;
                el[e] = (__float_as_uint(l0) >> 16) |
                        (__float_as_uint(l1) & 0xFFFF0000u);
            }
        }
    };
    // 5 LDS reads (Bh) -> bf[], hh pass (15 indep), lh pass (15 indep),
    // reload bf[] from Bl, hl pass (15 indep). Only 20 extra VGPRs live.
    auto MFMASTEP = [&](int b, short8* aH, short8* aL) {
        short8 bf[5];
#pragma unroll
        for (int nf = 0; nf < 5; ++nf)
            bf[nf] = *(const short8*)&Bh[b][(nf * 16 + lr) * 40 + lc * 8];
#pragma unroll
        for (int nf = 0; nf < 5; ++nf)
#pragma unroll
            for (int mf = 0; mf < 3; ++mf)
                acc[mf][nf] = MFMA(aH[mf], bf[nf], acc[mf][nf]);
#pragma unroll
        for (int nf = 0; nf < 5; ++nf)
#pragma unroll
            for (int mf = 0; mf < 3; ++mf)
                acc[mf][nf] = MFMA(aL[mf], bf[nf], acc[mf][nf]);
#pragma unroll
        for (int nf = 0; nf < 5; ++nf)
            bf[nf] = *(const short8*)&Bl[b][(nf * 16 + lr) * 40 + lc * 8];
#pragma unroll
        for (int nf = 0; nf < 5; ++nf)
#pragma unroll
            for (int mf = 0; mf < 3; ++mf)
                acc[mf][nf] = MFMA(aH[mf], bf[nf], acc[mf][nf]);
    };

    // ping/pong register stages: slot parity == step parity
    short8 aH0[3], aL0[3], aH1[3], aL1[3];
    float4 vA0, vB0, vA1, vB1;

    LOADA(aH0, aL0, 0); LOADA(aH1, aL1, 1);
    LOADV(vA0, vB0, 0); LOADV(vA1, vB1, 1);
    __syncthreads();                 // p_s + zero-pads visible
    BUILDW(0, vA0, vB0, 0);          // only stall-on-load BUILD (prologue)
    LOADV(vA0, vB0, 2);
    __syncthreads();                 // buf0 visible

#pragma unroll
    for (int tt = 0; tt < 6; ++tt) {
        int t0 = tt * 2, t1 = tt * 2 + 1;
        // even step t0: MFMA buf0/slot0; BUILD t0+1 -> buf1 from slot1
        BUILDW(1, vA1, vB1, t0 + 1);
        if (t0 + 3 <= 11) LOADV(vA1, vB1, t0 + 3);
        MFMASTEP(0, aH0, aL0);
        if (t0 + 2 <= 11) LOADA(aH0, aL0, t0 + 2);
        __syncthreads();
        // odd step t1: MFMA buf1/slot1; BUILD t1+1 -> buf0 from slot0
        if (t1 < 11) BUILDW(0, vA0, vB0, t1 + 1);
        if (t1 + 3 <= 11) LOADV(vA0, vB0, t1 + 3);
        MFMASTEP(1, aH1, aL1);
        if (t1 + 2 <= 11) LOADA(aH1, aL1, t1 + 2);
        __syncthreads();
    }

    // epilogue: s[n] = sum over this wave's 48 j of R*v1*T ; den via col 64.
    // acc[mf][nf] reg r <-> j = j0+mf*16+lc*4+r, col = nf*16+lr.
    float4 rj[3];
#pragma unroll
    for (int mf = 0; mf < 3; ++mf)
        rj[mf] = *(const float4*)(R + i * NN + j0 + mf * 16 + lc * 4);

#pragma unroll
    for (int nf = 0; nf < 5; ++nf) {
        float s = 0.f;
#pragma unroll
        for (int mf = 0; mf < 3; ++mf) {
            f32x4 a = acc[mf][nf];
            if (nf < 4) {
                const float* vp = v1t + (nf * 16 + lr) * NN + j0 + mf * 16 + lc * 4;
                float4 v1v = *(const float4*)vp;
                s += a[0] * rj[mf].x * v1v.x + a[1] * rj[mf].y * v1v.y
                   + a[2] * rj[mf].z * v1v.z + a[3] * rj[mf].w * v1v.w;
            } else {
                s += a[0] * rj[mf].x + a[1] * rj[mf].y
                   + a[2] * rj[mf].z + a[3] * rj[mf].w;
            }
        }
        s += __shfl_xor(s, 16, 64);
        s += __shfl_xor(s, 32, 64);
        if (l < 16) sh[w][nf * 16 + l] = s;
    }
    __syncthreads();
    if (tid < 80) {
        float v = sh[0][tid] + sh[1][tid] + sh[2][tid] + sh[3][tid];
        if (tid < 64) (jh ? num1 : num0)[i * 64 + tid] = v;
        else if (tid == 64) (jh ? den1 : den0)[i] = v;
    }
}

// ---------------- kernel 4: out = (num0+num1)/(den0+den1) ----------------
__global__ void finalize_kernel(const float* __restrict__ num0, const float* __restrict__ num1,
                                const float* __restrict__ den0, const float* __restrict__ den1,
                                float* __restrict__ out) {
    int idx = blockIdx.x * 256 + threadIdx.x;   // 24576
    int i = idx >> 6;
    out[idx] = (num0[idx] + num1[idx]) / (den0[i] + den1[i]);
}

extern "C" void kernel_launch(void* const* d_in, const int* in_sizes, int n_in,
                              void* d_out, int out_size, void* d_ws, size_t ws_size,
                              hipStream_t stream) {
    const float* x = (const float*)d_in[0];      // [1,384,64]
    const float* W = (const float*)d_in[1];      // [512,64]
    float* out = (float*)d_out;                  // [384,64]

    float* ws   = (float*)d_ws;
    float* R    = ws;                            // 147456
    float* P    = ws + 147456;                   // 147456
    float* v1t  = ws + 294912;                   // 24576  [64][384]
    float* v2t  = ws + 319488;                   // 24576  [64][384]
    u16*   Qhi  = (u16*)(ws + 344064);           // 147456 u16
    u16*   Qlo  = (u16*)(ws + 417792);           // 147456 u16
    float* proj = ws + 491520;                   // 196608
    // partials alias proj (proj dead after scores_exp)
    float* num0 = proj;                          // 24576
    float* num1 = proj + 24576;                  // 24576
    float* den0 = proj + 49152;                  // 384
    float* den1 = proj + 49536;                  // 384

    proj_kernel<<<NN, 256, 0, stream>>>(x, W, proj, v1t, v2t);
    scores_exp_kernel<<<dim3(12, 12, 3), 256, 0, stream>>>(proj, R, P, Qhi, Qlo);
    main_mfma<<<768, 256, 0, stream>>>(Qhi, Qlo, R, P, v1t, v2t,
                                       num0, num1, den0, den1);
    finalize_kernel<<<96, 256, 0, stream>>>(num0, num1, den0, den1, out);
}

// Round 8
// 106.883 us; speedup vs baseline: 1.3671x; 1.0315x over previous
//
#include <hip/hip_runtime.h>
#include <math.h>

// TripleAttention: B=1, N=384, C=D=64, H=1.
// out[i,d] = num/den,
//   num[i,d] = sum_{j,k} R[i,j] P[i,k] Q[j,k] v1[j,d] v2[k,d]
//   den[i]   = sum_{j,k} R[i,j] P[i,k] Q[j,k]
// R=exp(AB), P=exp(CD), Q=exp(EF); reference's global-max shift cancels in the
// ratio. Main contraction: bf16 MFMA, hi/lo split (3 products) ~2^-16 accuracy.
// Round 8: counted-vmcnt barriers (T4). K-loop barriers are raw
// {sched_barrier; s_waitcnt lgkmcnt(0); s_barrier; sched_barrier} so global
// A/V prefetches are NOT drained at barriers (HIP __syncthreads emits
// vmcnt(0)). Pipeline: A ping/pong 1-deep, V single-slot -> ~160 regs, no spill.

#define NN 384

using short8 = __attribute__((ext_vector_type(8))) short;
using f32x4  = __attribute__((ext_vector_type(4))) float;
typedef unsigned short u16;
typedef unsigned int u32;

// ---------------- kernel 1: proj = x @ W^T  [384,512]; also v1t/v2t ----------------
__global__ void proj_kernel(const float* __restrict__ x, const float* __restrict__ W,
                            float* __restrict__ proj, float* __restrict__ v1t,
                            float* __restrict__ v2t) {
    int n = blockIdx.x;
    __shared__ float xs[64];
    if (threadIdx.x < 64) xs[threadIdx.x] = x[n * 64 + threadIdx.x];
    __syncthreads();
    const float4* xv4 = (const float4*)xs;
    for (int r = 0; r < 2; ++r) {
        int o = threadIdx.x + r * 256;
        const float4* w4 = (const float4*)(W + o * 64);
        float s = 0.f;
#pragma unroll
        for (int c = 0; c < 16; ++c) {
            float4 wv = w4[c];
            float4 xv = xv4[c];
            s += wv.x * xv.x + wv.y * xv.y + wv.z * xv.z + wv.w * xv.w;
        }
        proj[n * 512 + o] = s;
        if (o >= 448)      v2t[(o - 448) * NN + n] = s;   // v2^T [d][k]
        else if (o >= 384) v1t[(o - 384) * NN + n] = s;   // v1^T [d][j]
    }
}

// ---------------- kernel 2: scores + exp (+ bf16 split for Q) ----------------
__global__ void scores_exp_kernel(const float* __restrict__ proj,
                                  float* __restrict__ R, float* __restrict__ P,
                                  u16* __restrict__ Qhi, u16* __restrict__ Qlo) {
    int m = blockIdx.z;
    int bi = blockIdx.y, bj = blockIdx.x;
    int tid = threadIdx.x;
    int tx = tid % 16, ty = tid / 16;
    int aoff, boff;
    if (m == 0)      { aoff = 0;   boff = 64;  }
    else if (m == 1) { aoff = 128; boff = 192; }
    else             { aoff = 256; boff = 320; }

    __shared__ float As[32][65], Bs[32][65];
    for (int r = 0; r < 8; ++r) {
        int idx = tid + r * 256;
        int row = idx / 64, col = idx % 64;
        As[row][col] = proj[(bi * 32 + row) * 512 + aoff + col];
        Bs[row][col] = proj[(bj * 32 + row) * 512 + boff + col];
    }
    __syncthreads();

    float acc[2][2] = {{0.f, 0.f}, {0.f, 0.f}};
#pragma unroll 8
    for (int d = 0; d < 64; ++d) {
        float a0 = As[ty * 2][d], a1 = As[ty * 2 + 1][d];
        float b0 = Bs[tx * 2][d], b1 = Bs[tx * 2 + 1][d];
        acc[0][0] += a0 * b0; acc[0][1] += a0 * b1;
        acc[1][0] += a1 * b0; acc[1][1] += a1 * b1;
    }
#pragma unroll
    for (int a = 0; a < 2; ++a) {
        int row = bi * 32 + ty * 2 + a;
        int col = bj * 32 + tx * 2;
        float v0 = expf(acc[a][0] * 0.125f);
        float v1 = expf(acc[a][1] * 0.125f);
        if (m == 0) {
            R[row * NN + col] = v0; R[row * NN + col + 1] = v1;
        } else if (m == 1) {
            P[row * NN + col] = v0; P[row * NN + col + 1] = v1;
        } else {
            u32 b0 = __float_as_uint(v0), b1 = __float_as_uint(v1);
            u32 h0 = b0 & 0xFFFF0000u,   h1 = b1 & 0xFFFF0000u;
            float l0 = v0 - __uint_as_float(h0);
            float l1 = v1 - __uint_as_float(h1);
            ushort2 hw, lw;
            hw.x = (u16)(h0 >> 16); hw.y = (u16)(h1 >> 16);
            lw.x = (u16)(__float_as_uint(l0) >> 16);
            lw.y = (u16)(__float_as_uint(l1) >> 16);
            *(ushort2*)(Qhi + row * NN + col) = hw;
            *(ushort2*)(Qlo + row * NN + col) = lw;
        }
    }
}

#define MFMA(A, B, C) __builtin_amdgcn_mfma_f32_16x16x32_bf16(A, B, C, 0, 0, 0)

// Raw barrier: drain LDS only (lgkmcnt). Global prefetches stay in flight
// across the barrier (counted vmcnt at their use site) — the T4 lever.
#define LGKM_BARRIER() do {                                   \
    __builtin_amdgcn_sched_barrier(0);                        \
    asm volatile("s_waitcnt lgkmcnt(0)" ::: "memory");        \
    __builtin_amdgcn_s_barrier();                             \
    __builtin_amdgcn_sched_barrier(0);                        \
} while (0)

// ---------------- kernel 3: main MFMA contraction ----------------
// block = (i, jh): M=192 (j), N=80 (64 d + den col 64 + 15 zero), K=384.
__global__ __launch_bounds__(256, 3) void main_mfma(
    const u16* __restrict__ Qhi, const u16* __restrict__ Qlo,
    const float* __restrict__ R, const float* __restrict__ P,
    const float* __restrict__ v1t, const float* __restrict__ v2t,
    float* __restrict__ num0, float* __restrict__ num1,
    float* __restrict__ den0, float* __restrict__ den1) {
    int i  = blockIdx.x >> 1;
    int jh = blockIdx.x & 1;
    int tid = (int)threadIdx.x;
    int w = tid >> 6, l = tid & 63;
    int lr = l & 15, lc = l >> 4;
    int j0 = jh * 192 + w * 48;
    int kkq = (tid & 3) * 8;                 // BUILD k-offset within step
    int nB  = tid >> 2;                      // BUILD n-row (0..63)

    __shared__ float p_s[NN];
    __shared__ u16 Bh[2][80 * 40];
    __shared__ u16 Bl[2][80 * 40];
    __shared__ float sh[4][80];

    p_s[tid] = P[i * NN + tid];
    if (tid < 128) p_s[256 + tid] = P[i * NN + 256 + tid];
    // zero den-pad rows 65..79 of all 4 buffers once
    for (int z = tid; z < 1200; z += 256) {
        int m = z / 300, r = z % 300;
        u32* base = (u32*)((m & 1) ? Bl[m >> 1] : Bh[m >> 1]);
        base[1300 + r] = 0u;
    }

    const u16* qh_base = Qhi + (j0 + lr) * NN + lc * 8;
    const u16* ql_base = Qlo + (j0 + lr) * NN + lc * 8;
    const float* vt_base = v2t + nB * NN + kkq;

    f32x4 acc[3][5];
#pragma unroll
    for (int mf = 0; mf < 3; ++mf)
#pragma unroll
        for (int nf = 0; nf < 5; ++nf)
            acc[mf][nf] = (f32x4){0.f, 0.f, 0.f, 0.f};

    auto LOADA = [&](short8* H, short8* L, int t) {
#pragma unroll
        for (int mf = 0; mf < 3; ++mf) {
            H[mf] = *(const short8*)(qh_base + mf * 16 * NN + t * 32);
            L[mf] = *(const short8*)(ql_base + mf * 16 * NN + t * 32);
        }
    };
    auto LOADV = [&](float4& a, float4& b, int t) {
        a = *(const float4*)(vt_base + t * 32);
        b = *(const float4*)(vt_base + t * 32 + 4);
    };
    // BUILD from registers: VALU + ds_write only (p_s via LDS broadcast)
    auto BUILDW = [&](int buf, float4 va, float4 vb, int t) {
        int krel = t * 32;
        const float* pp = p_s + krel + kkq;
        float pr[8] = {va.x * pp[0], va.y * pp[1], va.z * pp[2], va.w * pp[3],
                       vb.x * pp[4], vb.y * pp[5], vb.z * pp[6], vb.w * pp[7]};
        u32* dh = (u32*)&Bh[buf][nB * 40 + kkq];
        u32* dl = (u32*)&Bl[buf][nB * 40 + kkq];
#pragma unroll
        for (int e = 0; e < 4; ++e) {
            float x0 = pr[2 * e], x1 = pr[2 * e + 1];
            u32 h0 = __float_as_uint(x0) & 0xFFFF0000u;
            u32 h1 = __float_as_uint(x1) & 0xFFFF0000u;
            float l0 = x0 - __uint_as_float(h0);
            float l1 = x1 - __uint_as_float(h1);
            dh[e] = (h0 >> 16) | h1;
            dl[e] = (__float_as_uint(l0) >> 16) |
                    (__float_as_uint(l1) & 0xFFFF0000u);
        }
        if (tid < 4) {       // den column 64: B = P
            const float* pq = p_s + krel + tid * 8;
            u32* eh = (u32*)&Bh[buf][64 * 40 + tid * 8];
            u32* el = (u32*)&Bl[buf][64 * 40 + tid * 8];
#pragma unroll
            for (int e = 0; e < 4; ++e) {
                float x0 = pq[2 * e], x1 = pq[2 * e + 1];
                u32 h0 = __float_as_uint(x0) & 0xFFFF0000u;
                u32 h1 = __float_as_uint(x1) & 0xFFFF0000u;
                float l0 = x0 - __uint_as_float(h0);
                float l1 = x1 - __uint_as_float(h1);
                eh[e] = (h0 >> 16) | h1;
                el[e] = (__float_as_uint(l0) >> 16) |
                        (__float_as_uint(l1) & 0xFFFF0000u);
            }
        }
    };
    // 5 LDS reads (Bh) -> bf[], hh pass (15 indep), lh pass (15 indep),
    // reload bf[] from Bl, hl pass (15 indep). 20 extra VGPRs live.
    auto MFMASTEP = [&](int b, short8* aH, short8* aL) {
        short8 bf[5];
#pragma unroll
        for (int nf = 0; nf < 5; ++nf)
            bf[nf] = *(const short8*)&Bh[b][(nf * 16 + lr) * 40 + lc * 8];
#pragma unroll
        for (int nf = 0; nf < 5; ++nf)
#pragma unroll
            for (int mf = 0; mf < 3; ++mf)
                acc[mf][nf] = MFMA(aH[mf], bf[nf], acc[mf][nf]);
#pragma unroll
        for (int nf = 0; nf < 5; ++nf)
#pragma unroll
            for (int mf = 0; mf < 3; ++mf)
                acc[mf][nf] = MFMA(aL[mf], bf[nf], acc[mf][nf]);
#pragma unroll
        for (int nf = 0; nf < 5; ++nf)
            bf[nf] = *(const short8*)&Bl[b][(nf * 16 + lr) * 40 + lc * 8];
#pragma unroll
        for (int nf = 0; nf < 5; ++nf)
#pragma unroll
            for (int mf = 0; mf < 3; ++mf)
                acc[mf][nf] = MFMA(aH[mf], bf[nf], acc[mf][nf]);
    };

    // ping/pong A slots (parity = step parity); single-slot V
    short8 aH0[3], aL0[3], aH1[3], aL1[3];
    float4 vA, vB;

    LOADA(aH0, aL0, 0);
    LOADV(vA, vB, 0);
    __syncthreads();                 // p_s + zero-pads visible (full barrier ok)
    BUILDW(0, vA, vB, 0);            // prologue BUILD (stalls on vA once)
    LOADV(vA, vB, 1);
    LOADA(aH1, aL1, 1);
    LGKM_BARRIER();                  // buf0 visible; A/V loads stay in flight

#define STEP(T, AH, AL)                                         \
    do {                                                        \
        if ((T) < 11) BUILDW((((T) & 1) ^ 1), vA, vB, (T) + 1); \
        if ((T) + 2 <= 11) LOADV(vA, vB, (T) + 2);              \
        MFMASTEP(((T) & 1), AH, AL);                            \
        if ((T) + 2 <= 11) LOADA(AH, AL, (T) + 2);              \
        LGKM_BARRIER();                                         \
    } while (0)

    STEP(0, aH0, aL0);
    STEP(1, aH1, aL1);
    STEP(2, aH0, aL0);
    STEP(3, aH1, aL1);
    STEP(4, aH0, aL0);
    STEP(5, aH1, aL1);
    STEP(6, aH0, aL0);
    STEP(7, aH1, aL1);
    STEP(8, aH0, aL0);
    STEP(9, aH1, aL1);
    STEP(10, aH0, aL0);
    STEP(11, aH1, aL1);
#undef STEP

    // epilogue: s[n] = sum over this wave's 48 j of R*v1*T ; den via col 64.
    // acc[mf][nf] reg r <-> j = j0+mf*16+lc*4+r, col = nf*16+lr.
    float4 rj[3];
#pragma unroll
    for (int mf = 0; mf < 3; ++mf)
        rj[mf] = *(const float4*)(R + i * NN + j0 + mf * 16 + lc * 4);

#pragma unroll
    for (int nf = 0; nf < 5; ++nf) {
        float s = 0.f;
#pragma unroll
        for (int mf = 0; mf < 3; ++mf) {
            f32x4 a = acc[mf][nf];
            if (nf < 4) {
                const float* vp = v1t + (nf * 16 + lr) * NN + j0 + mf * 16 + lc * 4;
                float4 v1v = *(const float4*)vp;
                s += a[0] * rj[mf].x * v1v.x + a[1] * rj[mf].y * v1v.y
                   + a[2] * rj[mf].z * v1v.z + a[3] * rj[mf].w * v1v.w;
            } else {
                s += a[0] * rj[mf].x + a[1] * rj[mf].y
                   + a[2] * rj[mf].z + a[3] * rj[mf].w;
            }
        }
        s += __shfl_xor(s, 16, 64);
        s += __shfl_xor(s, 32, 64);
        if (l < 16) sh[w][nf * 16 + l] = s;
    }
    __syncthreads();
    if (tid < 80) {
        float v = sh[0][tid] + sh[1][tid] + sh[2][tid] + sh[3][tid];
        if (tid < 64) (jh ? num1 : num0)[i * 64 + tid] = v;
        else if (tid == 64) (jh ? den1 : den0)[i] = v;
    }
}

// ---------------- kernel 4: out = (num0+num1)/(den0+den1) ----------------
__global__ void finalize_kernel(const float* __restrict__ num0, const float* __restrict__ num1,
                                const float* __restrict__ den0, const float* __restrict__ den1,
                                float* __restrict__ out) {
    int idx = blockIdx.x * 256 + threadIdx.x;   // 24576
    int i = idx >> 6;
    out[idx] = (num0[idx] + num1[idx]) / (den0[i] + den1[i]);
}

extern "C" void kernel_launch(void* const* d_in, const int* in_sizes, int n_in,
                              void* d_out, int out_size, void* d_ws, size_t ws_size,
                              hipStream_t stream) {
    const float* x = (const float*)d_in[0];      // [1,384,64]
    const float* W = (const float*)d_in[1];      // [512,64]
    float* out = (float*)d_out;                  // [384,64]

    float* ws   = (float*)d_ws;
    float* R    = ws;                            // 147456
    float* P    = ws + 147456;                   // 147456
    float* v1t  = ws + 294912;                   // 24576  [64][384]
    float* v2t  = ws + 319488;                   // 24576  [64][384]
    u16*   Qhi  = (u16*)(ws + 344064);           // 147456 u16
    u16*   Qlo  = (u16*)(ws + 417792);           // 147456 u16
    float* proj = ws + 491520;                   // 196608
    // partials alias proj (proj dead after scores_exp)
    float* num0 = proj;                          // 24576
    float* num1 = proj + 24576;                  // 24576
    float* den0 = proj + 49152;                  // 384
    float* den1 = proj + 49536;                  // 384

    proj_kernel<<<NN, 256, 0, stream>>>(x, W, proj, v1t, v2t);
    scores_exp_kernel<<<dim3(12, 12, 3), 256, 0, stream>>>(proj, R, P, Qhi, Qlo);
    main_mfma<<<768, 256, 0, stream>>>(Qhi, Qlo, R, P, v1t, v2t,
                                       num0, num1, den0, den1);
    finalize_kernel<<<96, 256, 0, stream>>>(num0, num1, den0, den1, out);
}